// Round 5
// baseline (314.750 us; speedup 1.0000x reference)
//
#include <hip/hip_runtime.h>
#include <hip/hip_bf16.h>

// SimpleAttention fused block on MI355X (gfx950), bf16 MFMA pipeline.
// B=2, S=2048, D_MODEL=2048, H=16, DK=128.
//
// R5: QKV gemm256 staging issued ALL-AT-TILE-START (drain at q==3 now waits on
//     loads ~3.5 phases old); out-proj back to 128^2 gemm_bt (512 blocks, full
//     GPU); rope_apply vectorized bf16x8.
//
// ws layout (bytes):          size
//  xb      [4096,2048] bf16    16M @ 0
//  wqkvb   [6144,2048] bf16    24M @ 16M
//  wob     [2048,2048] bf16     8M @ 40M
//  Qb  [B,H,S,128] bf16        16M @ 48M   (pre-rope from gemm, rope in place)
//  Kb  [B,H,S,128] bf16        16M @ 64M
//  Vt  [B,H,128,S] bf16        16M @ 80M
//  Ao  [B,S,2048]  bf16        16M @ 96M
//  ctab [2048,64] f32         512K @ 112M
//  stab [2048,64] f32         512K @ 113M

typedef __bf16 bf16;
typedef __bf16 bf16x4 __attribute__((ext_vector_type(4)));
typedef __bf16 bf16x8 __attribute__((ext_vector_type(8)));
typedef float f32x4 __attribute__((ext_vector_type(4)));
typedef float f32x16 __attribute__((ext_vector_type(16)));
typedef int i32x4 __attribute__((ext_vector_type(4)));

#define DEV __device__ __forceinline__

DEV void gll16(const void* g, void* lds_base_wave_uniform) {
  __builtin_amdgcn_global_load_lds((const __attribute__((address_space(1))) void*)g,
                                   (__attribute__((address_space(3))) void*)lds_base_wave_uniform,
                                   16, 0, 0);
}

DEV f32x4 mfma16(bf16x8 a, bf16x8 b, f32x4 c) {
  return __builtin_amdgcn_mfma_f32_16x16x32_bf16(a, b, c, 0, 0, 0);
}
DEV f32x16 mfma32(bf16x8 a, bf16x8 b, f32x16 c) {
  return __builtin_amdgcn_mfma_f32_32x32x16_bf16(a, b, c, 0, 0, 0);
}

DEV int pack2(float x, float y) {
  union { bf16 h[2]; int i; } u;
  u.h[0] = (bf16)x; u.h[1] = (bf16)y;
  return u.i;
}

// ---------------- f32 -> bf16 convert ----------------
__global__ __launch_bounds__(256) void cvt_f32_bf16(const float* __restrict__ in,
                                                    bf16* __restrict__ out, int n) {
  int i = (blockIdx.x * 256 + threadIdx.x) << 3;
  if (i >= n) return;
  float4 a = *(const float4*)(in + i);
  float4 b = *(const float4*)(in + i + 4);
  bf16x8 o;
  o[0] = (bf16)a.x; o[1] = (bf16)a.y; o[2] = (bf16)a.z; o[3] = (bf16)a.w;
  o[4] = (bf16)b.x; o[5] = (bf16)b.y; o[6] = (bf16)b.z; o[7] = (bf16)b.w;
  *(bf16x8*)(out + i) = o;
}

// ---------------- rope tables ----------------
// freq[j] = 10000^(-j/63)  (linspace(0,1,64) inclusive!)
__global__ __launch_bounds__(256) void rope_table(float* __restrict__ ctab,
                                                  float* __restrict__ stab) {
  int id = blockIdx.x * 256 + threadIdx.x;  // 2048*64
  int s = id >> 6, j = id & 63;
  float freq = powf(10000.0f, -(float)j / 63.0f);
  float th = (float)s * freq;
  ctab[id] = cosf(th);
  stab[id] = sinf(th);
}

// ---------------- in-place rope on Qb (with scale) and Kb, bf16x8 ----------------
__global__ __launch_bounds__(256) void rope_apply(bf16* __restrict__ Qb, bf16* __restrict__ Kb,
                                                  const float* __restrict__ ctab,
                                                  const float* __restrict__ stab) {
  const float QSCALE = 0.08838834764831845f * 1.4426950408889634f;
  int id = blockIdx.x * 256 + threadIdx.x;  // 2 * 32*2048*8
  const int half = 32 * 2048 * 8;
  bf16* P = (id < half) ? Qb : Kb;
  const float scale = (id < half) ? QSCALE : 1.0f;
  int t = (id < half) ? id : id - half;
  const int d0 = (t & 7) << 3;        // 8 rotary pairs per thread
  const int s = (t >> 3) & 2047;
  const int bh = t >> 14;
  bf16* p = P + (((size_t)bh * 2048 + s) << 7);
  bf16x8 x1 = *(bf16x8*)(p + d0);
  bf16x8 x2 = *(bf16x8*)(p + d0 + 64);
  float4 ca = *(const float4*)(ctab + (s << 6) + d0);
  float4 cb = *(const float4*)(ctab + (s << 6) + d0 + 4);
  float4 sa = *(const float4*)(stab + (s << 6) + d0);
  float4 sb = *(const float4*)(stab + (s << 6) + d0 + 4);
  const float c[8] = {ca.x, ca.y, ca.z, ca.w, cb.x, cb.y, cb.z, cb.w};
  const float sn[8] = {sa.x, sa.y, sa.z, sa.w, sb.x, sb.y, sb.z, sb.w};
  bf16x8 y1, y2;
#pragma unroll
  for (int j = 0; j < 8; ++j) {
    const float a = (float)x1[j], b = (float)x2[j];
    y1[j] = (bf16)((a * c[j] - b * sn[j]) * scale);
    y2[j] = (bf16)((a * sn[j] + b * c[j]) * scale);
  }
  *(bf16x8*)(p + d0) = y1;
  *(bf16x8*)(p + d0 + 64) = y2;
}

// ---------------- 128x128 GEMM (out-proj): C = A * Bt^T, f32 out ----------------
template <int NT>  // NT = N/128
__global__ __launch_bounds__(256) void gemm_bt(const bf16* __restrict__ A,
                                               const bf16* __restrict__ Bt,
                                               float* __restrict__ f_out) {
  constexpr int K = 2048;
  __shared__ bf16 As[128 * 64];
  __shared__ bf16 Bs[128 * 64];
  const int nwg = NT * 32;
  const int id = blockIdx.x;
  const int swz = (id & 7) * (nwg >> 3) + (id >> 3);  // XCD swizzle (nwg % 8 == 0)
  const int bx = swz % NT, by = swz / NT;
  const int m0 = by << 7, n0 = bx << 7;
  const int tid = threadIdx.x, w = tid >> 6, l = tid & 63;
  const int wr = w >> 1, wc = w & 1;

  f32x4 acc[4][4] = {};

#pragma unroll 1
  for (int kt = 0; kt < K / 64; ++kt) {
    __syncthreads();
    const int k0 = kt << 6;
#pragma unroll
    for (int i = 0; i < 4; ++i) {
      const int row = (w << 5) + (i << 3) + (l >> 3);  // 8 rows x 128B per inst
      const int blk = (l & 7) ^ (row & 7);
      gll16(A + (size_t)(m0 + row) * K + k0 + (blk << 3), (char*)As + (w << 12) + (i << 10));
      gll16(Bt + (size_t)(n0 + row) * K + k0 + (blk << 3), (char*)Bs + (w << 12) + (i << 10));
    }
    asm volatile("s_waitcnt vmcnt(0)" ::: "memory");
    __syncthreads();
#pragma unroll
    for (int ks = 0; ks < 2; ++ks) {
      bf16x8 a[4], b[4];
#pragma unroll
      for (int i = 0; i < 4; ++i) {
        const int ra = (wr << 6) + (i << 4) + (l & 15);
        a[i] = *(const bf16x8*)((const char*)As + ra * 128 +
                                (((ks << 6) + ((l >> 4) << 4)) ^ ((ra & 7) << 4)));
        const int rb = (wc << 6) + (i << 4) + (l & 15);
        b[i] = *(const bf16x8*)((const char*)Bs + rb * 128 +
                                (((ks << 6) + ((l >> 4) << 4)) ^ ((rb & 7) << 4)));
      }
#pragma unroll
      for (int i = 0; i < 4; ++i)
#pragma unroll
        for (int j = 0; j < 4; ++j)
          acc[i][j] = mfma16(a[i], b[j], acc[i][j]);
    }
  }

#pragma unroll
  for (int i = 0; i < 4; ++i)
#pragma unroll
    for (int j = 0; j < 4; ++j)
#pragma unroll
      for (int r = 0; r < 4; ++r) {
        const int m = m0 + (wr << 6) + (i << 4) + ((l >> 4) << 2) + r;
        const int n = n0 + (wc << 6) + (j << 4) + (l & 15);
        f_out[(size_t)m * 2048 + n] = acc[i][j][r];
      }
}

// ---------------- 256x256 8-phase GEMM (QKV): C = A * Bt^T ----------------
// 8 waves (2Mx4N), BK=64, dbuf 128KiB LDS, XOR swizzle. ALL 8 stage loads for
// tile t+1 issued at the TOP of tile t (before any ds_read) so the single
// vmcnt(0) at q==3 waits on ~3.5-phase-old loads. Scatter epilogue to
// Qb/Kb ([B,H,S,128]) and Vt ([B,H,128,S]).
template <int NT2>  // NT2 = N/256
__global__ __launch_bounds__(512, 2) void gemm256(const bf16* __restrict__ A,
                                                  const bf16* __restrict__ Bt,
                                                  bf16* __restrict__ q_out,
                                                  bf16* __restrict__ k_out,
                                                  bf16* __restrict__ v_out) {
  constexpr int K = 2048, NKT = 32;
  __shared__ bf16 As[2][256 * 64];  // 64 KiB
  __shared__ bf16 Bs[2][256 * 64];  // 64 KiB
  char* AsB = (char*)As;
  char* BsB = (char*)Bs;

  const int nwg = NT2 * 16;
  const int id = blockIdx.x;
  const int swz = (id & 7) * (nwg >> 3) + (id >> 3);  // XCD swizzle (nwg % 8 == 0)
  const int bx = swz % NT2, by = swz / NT2;
  const int m0 = by << 8, n0 = bx << 8;
  const int tid = threadIdx.x, w = tid >> 6, l = tid & 63;
  const int wm = w >> 2, wn = w & 3;
  const int colswz = ((tid & 7) ^ ((tid >> 3) & 7)) << 3;  // staging src column (elems)

  // stage half-tile q_: 0=A rows 0-127, 1=A rows 128-255, 2=B half0, 3=B half1
  auto STAGE = [&](int tt, int q_) {
    const int bb = tt & 1;
    const bf16* mat = (q_ < 2) ? A : Bt;
    const int off = (q_ < 2) ? m0 : n0;
    char* lbase = ((q_ < 2) ? AsB : BsB) + (bb << 15) + ((q_ & 1) << 14) + (w << 10);
#pragma unroll
    for (int c = 0; c < 2; ++c) {
      const int row = ((q_ & 1) << 7) + (c << 6) + (tid >> 3);
      gll16(mat + (size_t)(off + row) * K + (tt << 6) + colswz, lbase + (c << 13));
    }
  };

  f32x4 acc[8][4] = {};
  bf16x8 bfr[4][2];

  // prologue: stage tile 0 into buf 0
#pragma unroll
  for (int q = 0; q < 4; ++q) STAGE(0, q);
  asm volatile("s_waitcnt vmcnt(0)" ::: "memory");
  __builtin_amdgcn_s_barrier();

#pragma unroll 1
  for (int t = 0; t < NKT; ++t) {
    const int rb = (t & 1) << 15;  // read-buffer byte offset
    // issue ALL next-tile staging loads first (buf[(t+1)&1] readers done at
    // the barrier that closed tile t-1) -> max MFMA cover before the drain.
    if (t + 1 < NKT) {
#pragma unroll
      for (int q = 0; q < 4; ++q) STAGE(t + 1, q);
    }
#pragma unroll
    for (int q = 0; q < 4; ++q) {
      if (q == 0) {  // B fragments: once per K-tile (8 ds_read_b128)
#pragma unroll
        for (int j = 0; j < 4; ++j)
#pragma unroll
          for (int ks = 0; ks < 2; ++ks) {
            const int rbr = (wn << 6) + (j << 4) + (l & 15);
            bfr[j][ks] = *(const bf16x8*)(BsB + rb + rbr * 128 +
                                          (((ks << 6) + ((l >> 4) << 4)) ^ ((rbr & 7) << 4)));
          }
      }
      bf16x8 af[2][2];  // A fragments for this quadrant (4 ds_read_b128)
#pragma unroll
      for (int i = 0; i < 2; ++i)
#pragma unroll
        for (int ks = 0; ks < 2; ++ks) {
          const int rar = (wm << 7) + (q << 5) + (i << 4) + (l & 15);
          af[i][ks] = *(const bf16x8*)(AsB + rb + rar * 128 +
                                       (((ks << 6) + ((l >> 4) << 4)) ^ ((rar & 7) << 4)));
        }
      __builtin_amdgcn_s_barrier();
      asm volatile("s_waitcnt lgkmcnt(0)" ::: "memory");
      __builtin_amdgcn_s_setprio(1);
#pragma unroll
      for (int ks = 0; ks < 2; ++ks)
#pragma unroll
        for (int i = 0; i < 2; ++i)
#pragma unroll
          for (int j = 0; j < 4; ++j)
            acc[(q << 1) + i][j] = mfma16(af[i][ks], bfr[j][ks], acc[(q << 1) + i][j]);
      __builtin_amdgcn_s_setprio(0);
      if (q == 3) asm volatile("s_waitcnt vmcnt(0)" ::: "memory");
      __builtin_amdgcn_s_barrier();
    }
  }

  // epilogue: frag (i,j): m = m0+wm*128+i*16+(l>>4)*4+r, n = n0+wn*64+j*16+(l&15)
  const int which = n0 >> 11;  // 0=Q 1=K 2=V (256-tile stays within one region)
  if (which < 2) {
    bf16* dst = which ? k_out : q_out;
#pragma unroll
    for (int i = 0; i < 8; ++i)
#pragma unroll
      for (int j = 0; j < 4; ++j) {
        const int nl = n0 + (wn << 6) + (j << 4) + (l & 15);
        const int h = (nl >> 7) & 15, d = nl & 127;
#pragma unroll
        for (int r = 0; r < 4; ++r) {
          const int m = m0 + (wm << 7) + (i << 4) + ((l >> 4) << 2) + r;
          const int b_ = m >> 11, s = m & 2047;
          dst[(((size_t)((b_ << 4) | h)) * 2048 + s) * 128 + d] = (bf16)acc[i][j][r];
        }
      }
  } else {
#pragma unroll
    for (int i = 0; i < 8; ++i)
#pragma unroll
      for (int j = 0; j < 4; ++j) {
        const int nl = n0 + (wn << 6) + (j << 4) + (l & 15);
        const int h = (nl >> 7) & 15, d = nl & 127;
#pragma unroll
        for (int r = 0; r < 4; ++r) {
          const int m = m0 + (wm << 7) + (i << 4) + ((l >> 4) << 2) + r;
          const int b_ = m >> 11, s = m & 2047;
          v_out[((size_t)((b_ << 4) | h) << 18) + ((size_t)d << 11) + s] = (bf16)acc[i][j][r];
        }
      }
  }
}

// ---------------- causal flash attention, swapped-operand 32x32 ----------------
// grid 512 = B*H*16 q-tiles; 4 waves x QBLK=32 rows = QB 128; KVBLK=64.
// Q pre-scaled by 1/sqrt(dk)*log2e -> exp2 softmax.
__global__ __launch_bounds__(256, 2) void attn_kernel(const bf16* __restrict__ Qb,
                                                      const bf16* __restrict__ Kb,
                                                      const bf16* __restrict__ Vt,
                                                      bf16* __restrict__ Ao) {
  constexpr int S = 2048;
  __shared__ bf16 Ks[64 * 128];  // [kv][d], 256B rows, swizzled
  __shared__ bf16 Vs[128 * 64];  // [d][kv], 128B rows, swizzled
  const int idx = blockIdx.x;
  const int bh = idx >> 4;
  int qt = idx & 15;
  if (idx & 256) qt = 15 - qt;  // balance causal triangle
  const int q0 = qt << 7;
  const int tid = threadIdx.x, w = tid >> 6, l = tid & 63;
  const int hi = l >> 5;  // 0 = lanes 0-31, 1 = lanes 32-63
  const bf16* Qp = Qb + ((size_t)bh << 18);
  const bf16* Kp = Kb + ((size_t)bh << 18);
  const bf16* Vp = Vt + ((size_t)bh << 18);

  // Q fragments: lane holds q-row q0+w*32+(l&31), k = kt*16 + hi*8 .. +8
  bf16x8 qf[8];
#pragma unroll
  for (int kt = 0; kt < 8; ++kt)
    qf[kt] = *(const bf16x8*)(Qp + ((size_t)(q0 + (w << 5) + (l & 31)) << 7) + (kt << 4) + (hi << 3));

  f32x16 o[4] = {};
  float mrun = -3e38f, lrun = 0.f;

  const int qminw = q0 + (w << 5);   // wave's first q row
  const int qmaxw = qminw + 31;      // wave's last q row
  const int kv_end = q0 + 128;
#pragma unroll 1
  for (int kv0 = 0; kv0 < kv_end; kv0 += 64) {
    __syncthreads();
#pragma unroll
    for (int i = 0; i < 4; ++i) {
      const int rk = (w << 4) + (i << 2) + (l >> 4);  // K: 4 rows x 256B per inst
      gll16(Kp + ((size_t)(kv0 + rk) << 7) + (((l & 15) ^ (rk & 7)) << 3),
            (char*)Ks + (w << 12) + (i << 10));
      const int rv = (w << 5) + (i << 3) + (l >> 3);  // V: 8 rows x 128B per inst
      gll16(Vp + (size_t)rv * S + kv0 + (((l & 7) ^ (rv & 7)) << 3),
            (char*)Vs + (w << 12) + (i << 10));
    }
    asm volatile("s_waitcnt vmcnt(0)" ::: "memory");
    __syncthreads();
    if (kv0 <= qmaxw) {
      // ---- S^T = K x Q^T : q = lane&31 ----
      f32x16 sc0 = {}, sc1 = {};
#pragma unroll
      for (int kt = 0; kt < 8; ++kt) {
        const int rk0 = l & 31;
        const int coff = ((kt << 5) + (hi << 4));
        bf16x8 k0 = *(const bf16x8*)((const char*)Ks + (rk0 << 8) + (coff ^ ((rk0 & 7) << 4)));
        bf16x8 k1 = *(const bf16x8*)((const char*)Ks + ((rk0 + 32) << 8) + (coff ^ ((rk0 & 7) << 4)));
        sc0 = mfma32(k0, qf[kt], sc0);
        sc1 = mfma32(k1, qf[kt], sc1);
      }
      // ---- causal mask: needed iff tile's max kv exceeds wave's MIN q ----
      if (kv0 + 63 > qminw) {
        const int qg = qminw + (l & 31);
#pragma unroll
        for (int r = 0; r < 16; ++r) {
          const int kvr = kv0 + (r & 3) + ((r >> 2) << 3) + (hi << 2);
          if (kvr > qg) sc0[r] = -3e38f;
          if (kvr + 32 > qg) sc1[r] = -3e38f;
        }
      }
      // ---- online softmax: row = lane-local 32 values + partner lane ----
      float mx = -3e38f;
#pragma unroll
      for (int r = 0; r < 16; ++r) mx = fmaxf(mx, fmaxf(sc0[r], sc1[r]));
      mx = fmaxf(mx, __shfl_xor(mx, 32));
      const float mnew = fmaxf(mrun, mx);
      if (!__all(mx <= mrun)) {  // defer-rescale: skip O pass when max unchanged
        const float alpha = exp2f(mrun - mnew);
        lrun *= alpha;
#pragma unroll
        for (int dt = 0; dt < 4; ++dt) o[dt] *= alpha;
      }
      mrun = mnew;
      float ps = 0.f;
#pragma unroll
      for (int r = 0; r < 16; ++r) {
        sc0[r] = exp2f(sc0[r] - mnew); ps += sc0[r];
        sc1[r] = exp2f(sc1[r] - mnew); ps += sc1[r];
      }
      ps += __shfl_xor(ps, 32);
      lrun += ps;
      // ---- O^T += V^T x P^T : P fragments assembled in-register ----
#pragma unroll
      for (int ks = 0; ks < 4; ++ks) {
        const f32x16& s = (ks & 2) ? sc1 : sc0;
        const int rb = (ks & 1) << 3;
        int pa_ = pack2(s[rb + 0], s[rb + 1]);
        int pb_ = pack2(s[rb + 2], s[rb + 3]);
        int pc_ = pack2(s[rb + 4], s[rb + 5]);
        int pd_ = pack2(s[rb + 6], s[rb + 7]);
        int sa = __shfl_xor(pa_, 32), sb = __shfl_xor(pb_, 32);
        int sc_ = __shfl_xor(pc_, 32), sd = __shfl_xor(pd_, 32);
        i32x4 pi;
        pi[0] = hi ? sc_ : pa_;
        pi[1] = hi ? sd : pb_;
        pi[2] = hi ? pc_ : sa;
        pi[3] = hi ? pd_ : sb;
        const bf16x8 pf = __builtin_bit_cast(bf16x8, pi);
#pragma unroll
        for (int dt = 0; dt < 4; ++dt) {
          const int rd = (dt << 5) + (l & 31);
          const bf16x8 vf = *(const bf16x8*)((const char*)Vs + (rd << 7) +
                                             (((ks << 5) + (hi << 4)) ^ ((rd & 7) << 4)));
          o[dt] = mfma32(vf, pf, o[dt]);
        }
      }
    }
  }
  // ---- epilogue: lane q = l&31, d = dt*32 + (r&3) + 8*(r>>2) + 4*hi ----
  const float rinv = 1.0f / lrun;
  const int b = bh >> 4, h = bh & 15;
  const int qg = q0 + (w << 5) + (l & 31);
  bf16* Arow = Ao + (((size_t)(b * S + qg)) << 11) + (h << 7);
#pragma unroll
  for (int dt = 0; dt < 4; ++dt)
#pragma unroll
    for (int g = 0; g < 4; ++g) {
      bf16x4 ov;
#pragma unroll
      for (int r = 0; r < 4; ++r) ov[r] = (bf16)(o[dt][(g << 2) + r] * rinv);
      *(bf16x4*)(Arow + (dt << 5) + (g << 3) + (hi << 2)) = ov;
    }
}

// ---------------- launch ----------------
extern "C" void kernel_launch(void* const* d_in, const int* in_sizes, int n_in,
                              void* d_out, int out_size, void* d_ws, size_t ws_size,
                              hipStream_t stream) {
  const float* x = (const float*)d_in[0];      // [2,2048,2048]
  const float* w_qkv = (const float*)d_in[1];  // [6144,2048]
  const float* w_o = (const float*)d_in[2];    // [2048,2048]
  float* out = (float*)d_out;                  // [2,2048,2048] f32
  char* ws = (char*)d_ws;

  bf16* xb    = (bf16*)(ws);
  bf16* wqkvb = (bf16*)(ws + (16ull << 20));
  bf16* wob   = (bf16*)(ws + (40ull << 20));
  bf16* Qb    = (bf16*)(ws + (48ull << 20));
  bf16* Kb    = (bf16*)(ws + (64ull << 20));
  bf16* Vt    = (bf16*)(ws + (80ull << 20));
  bf16* Ao    = (bf16*)(ws + (96ull << 20));
  float* ctab = (float*)(ws + (112ull << 20));
  float* stab = (float*)(ws + (113ull << 20));

  cvt_f32_bf16<<<4096, 256, 0, stream>>>(x, xb, 2 * 2048 * 2048);
  cvt_f32_bf16<<<6144, 256, 0, stream>>>(w_qkv, wqkvb, 6144 * 2048);
  cvt_f32_bf16<<<2048, 256, 0, stream>>>(w_o, wob, 2048 * 2048);
  rope_table<<<512, 256, 0, stream>>>(ctab, stab);
  gemm256<24><<<384, 512, 0, stream>>>(xb, wqkvb, Qb, Kb, Vt);
  rope_apply<<<4096, 256, 0, stream>>>(Qb, Kb, ctab, stab);
  attn_kernel<<<512, 256, 0, stream>>>(Qb, Kb, Vt, Ao);
  gemm_bt<16><<<512, 256, 0, stream>>>(Ao, wob, out);
}

// Round 6
// 284.386 us; speedup vs baseline: 1.1068x; 1.1068x over previous
//
#include <hip/hip_runtime.h>
#include <hip/hip_bf16.h>

// SimpleAttention fused block on MI355X (gfx950), bf16 MFMA pipeline.
// B=2, S=2048, D_MODEL=2048, H=16, DK=128.
//
// R6: QKV gemm256 rebuilt on the true m201 8-phase schedule:
//   half-granular staging TWO K-tiles ahead, counted vmcnt(6) at K-tile
//   boundaries (never 0 in steady state), per-phase {ds_read | stage 1 half |
//   barrier | lgkmcnt | 16 MFMA | barrier}. Half order [B0,B1,A0,A1]:
//   B LDS-read only at ph0, A rows {0-1,2-3,4-7} at ph{0,1,2} -> WAR-safe.
//
// ws layout (bytes):          size
//  xb      [4096,2048] bf16    16M @ 0
//  wqkvb   [6144,2048] bf16    24M @ 16M
//  wob     [2048,2048] bf16     8M @ 40M
//  Qb  [B,H,S,128] bf16        16M @ 48M
//  Kb  [B,H,S,128] bf16        16M @ 64M
//  Vt  [B,H,128,S] bf16        16M @ 80M
//  Ao  [B,S,2048]  bf16        16M @ 96M
//  ctab [2048,64] f32         512K @ 112M
//  stab [2048,64] f32         512K @ 113M

typedef __bf16 bf16;
typedef __bf16 bf16x4 __attribute__((ext_vector_type(4)));
typedef __bf16 bf16x8 __attribute__((ext_vector_type(8)));
typedef float f32x4 __attribute__((ext_vector_type(4)));
typedef float f32x16 __attribute__((ext_vector_type(16)));
typedef int i32x4 __attribute__((ext_vector_type(4)));

#define DEV __device__ __forceinline__

DEV void gll16(const void* g, void* lds_base_wave_uniform) {
  __builtin_amdgcn_global_load_lds((const __attribute__((address_space(1))) void*)g,
                                   (__attribute__((address_space(3))) void*)lds_base_wave_uniform,
                                   16, 0, 0);
}

DEV f32x4 mfma16(bf16x8 a, bf16x8 b, f32x4 c) {
  return __builtin_amdgcn_mfma_f32_16x16x32_bf16(a, b, c, 0, 0, 0);
}
DEV f32x16 mfma32(bf16x8 a, bf16x8 b, f32x16 c) {
  return __builtin_amdgcn_mfma_f32_32x32x16_bf16(a, b, c, 0, 0, 0);
}

DEV int pack2(float x, float y) {
  union { bf16 h[2]; int i; } u;
  u.h[0] = (bf16)x; u.h[1] = (bf16)y;
  return u.i;
}

// ---------------- f32 -> bf16 convert ----------------
__global__ __launch_bounds__(256) void cvt_f32_bf16(const float* __restrict__ in,
                                                    bf16* __restrict__ out, int n) {
  int i = (blockIdx.x * 256 + threadIdx.x) << 3;
  if (i >= n) return;
  float4 a = *(const float4*)(in + i);
  float4 b = *(const float4*)(in + i + 4);
  bf16x8 o;
  o[0] = (bf16)a.x; o[1] = (bf16)a.y; o[2] = (bf16)a.z; o[3] = (bf16)a.w;
  o[4] = (bf16)b.x; o[5] = (bf16)b.y; o[6] = (bf16)b.z; o[7] = (bf16)b.w;
  *(bf16x8*)(out + i) = o;
}

// ---------------- rope tables ----------------
// freq[j] = 10000^(-j/63)  (linspace(0,1,64) inclusive!)
__global__ __launch_bounds__(256) void rope_table(float* __restrict__ ctab,
                                                  float* __restrict__ stab) {
  int id = blockIdx.x * 256 + threadIdx.x;  // 2048*64
  int s = id >> 6, j = id & 63;
  float freq = powf(10000.0f, -(float)j / 63.0f);
  float th = (float)s * freq;
  ctab[id] = cosf(th);
  stab[id] = sinf(th);
}

// ---------------- in-place rope on Qb (with scale) and Kb, bf16x8 ----------------
__global__ __launch_bounds__(256) void rope_apply(bf16* __restrict__ Qb, bf16* __restrict__ Kb,
                                                  const float* __restrict__ ctab,
                                                  const float* __restrict__ stab) {
  const float QSCALE = 0.08838834764831845f * 1.4426950408889634f;
  int id = blockIdx.x * 256 + threadIdx.x;  // 2 * 32*2048*8
  const int half = 32 * 2048 * 8;
  bf16* P = (id < half) ? Qb : Kb;
  const float scale = (id < half) ? QSCALE : 1.0f;
  int t = (id < half) ? id : id - half;
  const int d0 = (t & 7) << 3;        // 8 rotary pairs per thread
  const int s = (t >> 3) & 2047;
  const int bh = t >> 14;
  bf16* p = P + (((size_t)bh * 2048 + s) << 7);
  bf16x8 x1 = *(bf16x8*)(p + d0);
  bf16x8 x2 = *(bf16x8*)(p + d0 + 64);
  float4 ca = *(const float4*)(ctab + (s << 6) + d0);
  float4 cb = *(const float4*)(ctab + (s << 6) + d0 + 4);
  float4 sa = *(const float4*)(stab + (s << 6) + d0);
  float4 sb = *(const float4*)(stab + (s << 6) + d0 + 4);
  const float c[8] = {ca.x, ca.y, ca.z, ca.w, cb.x, cb.y, cb.z, cb.w};
  const float sn[8] = {sa.x, sa.y, sa.z, sa.w, sb.x, sb.y, sb.z, sb.w};
  bf16x8 y1, y2;
#pragma unroll
  for (int j = 0; j < 8; ++j) {
    const float a = (float)x1[j], b = (float)x2[j];
    y1[j] = (bf16)((a * c[j] - b * sn[j]) * scale);
    y2[j] = (bf16)((a * sn[j] + b * c[j]) * scale);
  }
  *(bf16x8*)(p + d0) = y1;
  *(bf16x8*)(p + d0 + 64) = y2;
}

// ---------------- 128x128 GEMM (out-proj): C = A * Bt^T, f32 out ----------------
template <int NT>  // NT = N/128
__global__ __launch_bounds__(256) void gemm_bt(const bf16* __restrict__ A,
                                               const bf16* __restrict__ Bt,
                                               float* __restrict__ f_out) {
  constexpr int K = 2048;
  __shared__ bf16 As[128 * 64];
  __shared__ bf16 Bs[128 * 64];
  const int nwg = NT * 32;
  const int id = blockIdx.x;
  const int swz = (id & 7) * (nwg >> 3) + (id >> 3);  // XCD swizzle (nwg % 8 == 0)
  const int bx = swz % NT, by = swz / NT;
  const int m0 = by << 7, n0 = bx << 7;
  const int tid = threadIdx.x, w = tid >> 6, l = tid & 63;
  const int wr = w >> 1, wc = w & 1;

  f32x4 acc[4][4] = {};

#pragma unroll 1
  for (int kt = 0; kt < K / 64; ++kt) {
    __syncthreads();
    const int k0 = kt << 6;
#pragma unroll
    for (int i = 0; i < 4; ++i) {
      const int row = (w << 5) + (i << 3) + (l >> 3);  // 8 rows x 128B per inst
      const int blk = (l & 7) ^ (row & 7);
      gll16(A + (size_t)(m0 + row) * K + k0 + (blk << 3), (char*)As + (w << 12) + (i << 10));
      gll16(Bt + (size_t)(n0 + row) * K + k0 + (blk << 3), (char*)Bs + (w << 12) + (i << 10));
    }
    asm volatile("s_waitcnt vmcnt(0)" ::: "memory");
    __syncthreads();
#pragma unroll
    for (int ks = 0; ks < 2; ++ks) {
      bf16x8 a[4], b[4];
#pragma unroll
      for (int i = 0; i < 4; ++i) {
        const int ra = (wr << 6) + (i << 4) + (l & 15);
        a[i] = *(const bf16x8*)((const char*)As + ra * 128 +
                                (((ks << 6) + ((l >> 4) << 4)) ^ ((ra & 7) << 4)));
        const int rb = (wc << 6) + (i << 4) + (l & 15);
        b[i] = *(const bf16x8*)((const char*)Bs + rb * 128 +
                                (((ks << 6) + ((l >> 4) << 4)) ^ ((rb & 7) << 4)));
      }
#pragma unroll
      for (int i = 0; i < 4; ++i)
#pragma unroll
        for (int j = 0; j < 4; ++j)
          acc[i][j] = mfma16(a[i], b[j], acc[i][j]);
    }
  }

#pragma unroll
  for (int i = 0; i < 4; ++i)
#pragma unroll
    for (int j = 0; j < 4; ++j)
#pragma unroll
      for (int r = 0; r < 4; ++r) {
        const int m = m0 + (wr << 6) + (i << 4) + ((l >> 4) << 2) + r;
        const int n = n0 + (wc << 6) + (j << 4) + (l & 15);
        f_out[(size_t)m * 2048 + n] = acc[i][j][r];
      }
}

// ---------------- 256x256 8-phase GEMM (QKV): C = A * Bt^T ----------------
// m201 schedule. 8 waves (wm=w>>2, wn=w&3); per-wave C = 128x64.
// Halves per K-tile: s 0=B0(rows0-127) 1=B1 2=A0 3=A1; staged 2 tiles ahead:
// tile t's phases stage {A1[t+1], B0[t+2], B1[t+2], A0[t+2]}.
// Reads: ph0 = all B (8) + A frag-rows 0-1 (4); ph1 = rows 2-3; ph2 = rows 4-7;
// ph3 = none. Boundary: vmcnt(6) (3 halves in flight), vmcnt(0) at t=NKT-2.
template <int NT2>  // NT2 = N/256
__global__ __launch_bounds__(512, 2) void gemm256(const bf16* __restrict__ A,
                                                  const bf16* __restrict__ Bt,
                                                  bf16* __restrict__ q_out,
                                                  bf16* __restrict__ k_out,
                                                  bf16* __restrict__ v_out) {
  constexpr int K = 2048, NKT = 32;
  __shared__ bf16 As[2][256 * 64];  // 64 KiB
  __shared__ bf16 Bs[2][256 * 64];  // 64 KiB
  char* AsB = (char*)As;
  char* BsB = (char*)Bs;

  const int nwg = NT2 * 16;
  const int id = blockIdx.x;
  const int swz = (id & 7) * (nwg >> 3) + (id >> 3);  // XCD swizzle (nwg % 8 == 0)
  const int bx = swz % NT2, by = swz / NT2;
  const int m0 = by << 8, n0 = bx << 8;
  const int tid = threadIdx.x, w = tid >> 6, l = tid & 63;
  const int wm = w >> 2, wn = w & 3;
  const int colswz = ((tid & 7) ^ ((tid >> 3) & 7)) << 3;  // staging src column (elems)

  // stage half s of K-tile `tile` into buf[tile&1]; 2 gll16 per thread.
  auto STAGE_H = [&](int tile, int s_) {
    const bf16* mat = (s_ < 2) ? Bt : A;
    const int off = (s_ < 2) ? n0 : m0;
    char* lbase = ((s_ < 2) ? BsB : AsB) + ((tile & 1) << 15) + ((s_ & 1) << 14) + (w << 10);
    const int rbase = (s_ & 1) << 7;
#pragma unroll
    for (int c = 0; c < 2; ++c) {
      const int row = rbase + (c << 6) + (tid >> 3);
      gll16(mat + (size_t)(off + row) * K + (tile << 6) + colswz, lbase + (c << 13));
    }
  };

  f32x4 acc[8][4] = {};

  // prologue: tile0 all 4 halves, then tile1 halves B0,B1,A0
#pragma unroll
  for (int s_ = 0; s_ < 4; ++s_) STAGE_H(0, s_);
  asm volatile("s_waitcnt vmcnt(4)" ::: "memory");
#pragma unroll
  for (int s_ = 0; s_ < 3; ++s_) STAGE_H(1, s_);
  asm volatile("s_waitcnt vmcnt(6)" ::: "memory");
  __builtin_amdgcn_s_barrier();

#pragma unroll 1
  for (int t = 0; t < NKT; ++t) {
    const int rbuf = (t & 1) << 15;
    bf16x8 bfr[4][2], af[8][2];
#pragma unroll
    for (int p = 0; p < 4; ++p) {
      // ---- ds_reads for this phase ----
      if (p == 0) {
#pragma unroll
        for (int j = 0; j < 4; ++j)
#pragma unroll
          for (int ks = 0; ks < 2; ++ks) {
            const int rbr = (wn << 6) + (j << 4) + (l & 15);
            bfr[j][ks] = *(const bf16x8*)(BsB + rbuf + rbr * 128 +
                                          (((ks << 6) + ((l >> 4) << 4)) ^ ((rbr & 7) << 4)));
          }
      }
      const int ra0 = (p == 2) ? 4 : (p << 1);      // first A frag-row this phase
      const int rn = (p == 2) ? 4 : (p == 3 ? 0 : 2);  // count
#pragma unroll
      for (int i = 0; i < 4; ++i) {
        if (i < rn) {
          const int fr = ra0 + i;
          const int rar = (wm << 7) + (fr << 4) + (l & 15);
#pragma unroll
          for (int ks = 0; ks < 2; ++ks)
            af[fr][ks] = *(const bf16x8*)(AsB + rbuf + rar * 128 +
                                          (((ks << 6) + ((l >> 4) << 4)) ^ ((rar & 7) << 4)));
        }
      }
      // ---- stage one half (2 tiles ahead, sequence G = 4t+7+p) ----
      {
        const int G = (t << 2) + 7 + p;
        if (G < (NKT << 2)) STAGE_H(G >> 2, G & 3);
      }
      __builtin_amdgcn_s_barrier();
      asm volatile("s_waitcnt lgkmcnt(0)" ::: "memory");
      __builtin_amdgcn_s_setprio(1);
#pragma unroll
      for (int ks = 0; ks < 2; ++ks)
#pragma unroll
        for (int i2 = 0; i2 < 2; ++i2)
#pragma unroll
          for (int j = 0; j < 4; ++j)
            acc[(p << 1) + i2][j] =
                mfma16(af[(p << 1) + i2][ks], bfr[j][ks], acc[(p << 1) + i2][j]);
      __builtin_amdgcn_s_setprio(0);
      if (p == 3) {
        if (t < NKT - 2) {
          asm volatile("s_waitcnt vmcnt(6)" ::: "memory");
        } else if (t == NKT - 2) {
          asm volatile("s_waitcnt vmcnt(0)" ::: "memory");
        }
      }
      __builtin_amdgcn_s_barrier();
    }
  }

  // epilogue: frag (i,j): m = m0+wm*128+i*16+(l>>4)*4+r, n = n0+wn*64+j*16+(l&15)
  const int which = n0 >> 11;  // 0=Q 1=K 2=V (256-tile stays within one region)
  if (which < 2) {
    bf16* dst = which ? k_out : q_out;
#pragma unroll
    for (int i = 0; i < 8; ++i)
#pragma unroll
      for (int j = 0; j < 4; ++j) {
        const int nl = n0 + (wn << 6) + (j << 4) + (l & 15);
        const int h = (nl >> 7) & 15, d = nl & 127;
#pragma unroll
        for (int r = 0; r < 4; ++r) {
          const int m = m0 + (wm << 7) + (i << 4) + ((l >> 4) << 2) + r;
          const int b_ = m >> 11, s = m & 2047;
          dst[(((size_t)((b_ << 4) | h)) * 2048 + s) * 128 + d] = (bf16)acc[i][j][r];
        }
      }
  } else {
#pragma unroll
    for (int i = 0; i < 8; ++i)
#pragma unroll
      for (int j = 0; j < 4; ++j) {
        const int nl = n0 + (wn << 6) + (j << 4) + (l & 15);
        const int h = (nl >> 7) & 15, d = nl & 127;
#pragma unroll
        for (int r = 0; r < 4; ++r) {
          const int m = m0 + (wm << 7) + (i << 4) + ((l >> 4) << 2) + r;
          const int b_ = m >> 11, s = m & 2047;
          v_out[((size_t)((b_ << 4) | h) << 18) + ((size_t)d << 11) + s] = (bf16)acc[i][j][r];
        }
      }
  }
}

// ---------------- causal flash attention, swapped-operand 32x32 ----------------
// grid 512 = B*H*16 q-tiles; 4 waves x QBLK=32 rows = QB 128; KVBLK=64.
// Q pre-scaled by 1/sqrt(dk)*log2e -> exp2 softmax.
__global__ __launch_bounds__(256, 2) void attn_kernel(const bf16* __restrict__ Qb,
                                                      const bf16* __restrict__ Kb,
                                                      const bf16* __restrict__ Vt,
                                                      bf16* __restrict__ Ao) {
  constexpr int S = 2048;
  __shared__ bf16 Ks[64 * 128];  // [kv][d], 256B rows, swizzled
  __shared__ bf16 Vs[128 * 64];  // [d][kv], 128B rows, swizzled
  const int idx = blockIdx.x;
  const int bh = idx >> 4;
  int qt = idx & 15;
  if (idx & 256) qt = 15 - qt;  // balance causal triangle
  const int q0 = qt << 7;
  const int tid = threadIdx.x, w = tid >> 6, l = tid & 63;
  const int hi = l >> 5;  // 0 = lanes 0-31, 1 = lanes 32-63
  const bf16* Qp = Qb + ((size_t)bh << 18);
  const bf16* Kp = Kb + ((size_t)bh << 18);
  const bf16* Vp = Vt + ((size_t)bh << 18);

  // Q fragments: lane holds q-row q0+w*32+(l&31), k = kt*16 + hi*8 .. +8
  bf16x8 qf[8];
#pragma unroll
  for (int kt = 0; kt < 8; ++kt)
    qf[kt] = *(const bf16x8*)(Qp + ((size_t)(q0 + (w << 5) + (l & 31)) << 7) + (kt << 4) + (hi << 3));

  f32x16 o[4] = {};
  float mrun = -3e38f, lrun = 0.f;

  const int qminw = q0 + (w << 5);   // wave's first q row
  const int qmaxw = qminw + 31;      // wave's last q row
  const int kv_end = q0 + 128;
#pragma unroll 1
  for (int kv0 = 0; kv0 < kv_end; kv0 += 64) {
    __syncthreads();
#pragma unroll
    for (int i = 0; i < 4; ++i) {
      const int rk = (w << 4) + (i << 2) + (l >> 4);  // K: 4 rows x 256B per inst
      gll16(Kp + ((size_t)(kv0 + rk) << 7) + (((l & 15) ^ (rk & 7)) << 3),
            (char*)Ks + (w << 12) + (i << 10));
      const int rv = (w << 5) + (i << 3) + (l >> 3);  // V: 8 rows x 128B per inst
      gll16(Vp + (size_t)rv * S + kv0 + (((l & 7) ^ (rv & 7)) << 3),
            (char*)Vs + (w << 12) + (i << 10));
    }
    asm volatile("s_waitcnt vmcnt(0)" ::: "memory");
    __syncthreads();
    if (kv0 <= qmaxw) {
      // ---- S^T = K x Q^T : q = lane&31 ----
      f32x16 sc0 = {}, sc1 = {};
#pragma unroll
      for (int kt = 0; kt < 8; ++kt) {
        const int rk0 = l & 31;
        const int coff = ((kt << 5) + (hi << 4));
        bf16x8 k0 = *(const bf16x8*)((const char*)Ks + (rk0 << 8) + (coff ^ ((rk0 & 7) << 4)));
        bf16x8 k1 = *(const bf16x8*)((const char*)Ks + ((rk0 + 32) << 8) + (coff ^ ((rk0 & 7) << 4)));
        sc0 = mfma32(k0, qf[kt], sc0);
        sc1 = mfma32(k1, qf[kt], sc1);
      }
      // ---- causal mask: needed iff tile's max kv exceeds wave's MIN q ----
      if (kv0 + 63 > qminw) {
        const int qg = qminw + (l & 31);
#pragma unroll
        for (int r = 0; r < 16; ++r) {
          const int kvr = kv0 + (r & 3) + ((r >> 2) << 3) + (hi << 2);
          if (kvr > qg) sc0[r] = -3e38f;
          if (kvr + 32 > qg) sc1[r] = -3e38f;
        }
      }
      // ---- online softmax: row = lane-local 32 values + partner lane ----
      float mx = -3e38f;
#pragma unroll
      for (int r = 0; r < 16; ++r) mx = fmaxf(mx, fmaxf(sc0[r], sc1[r]));
      mx = fmaxf(mx, __shfl_xor(mx, 32));
      const float mnew = fmaxf(mrun, mx);
      if (!__all(mx <= mrun)) {  // defer-rescale: skip O pass when max unchanged
        const float alpha = exp2f(mrun - mnew);
        lrun *= alpha;
#pragma unroll
        for (int dt = 0; dt < 4; ++dt) o[dt] *= alpha;
      }
      mrun = mnew;
      float ps = 0.f;
#pragma unroll
      for (int r = 0; r < 16; ++r) {
        sc0[r] = exp2f(sc0[r] - mnew); ps += sc0[r];
        sc1[r] = exp2f(sc1[r] - mnew); ps += sc1[r];
      }
      ps += __shfl_xor(ps, 32);
      lrun += ps;
      // ---- O^T += V^T x P^T : P fragments assembled in-register ----
#pragma unroll
      for (int ks = 0; ks < 4; ++ks) {
        const f32x16& s = (ks & 2) ? sc1 : sc0;
        const int rb = (ks & 1) << 3;
        int pa_ = pack2(s[rb + 0], s[rb + 1]);
        int pb_ = pack2(s[rb + 2], s[rb + 3]);
        int pc_ = pack2(s[rb + 4], s[rb + 5]);
        int pd_ = pack2(s[rb + 6], s[rb + 7]);
        int sa = __shfl_xor(pa_, 32), sb = __shfl_xor(pb_, 32);
        int sc_ = __shfl_xor(pc_, 32), sd = __shfl_xor(pd_, 32);
        i32x4 pi;
        pi[0] = hi ? sc_ : pa_;
        pi[1] = hi ? sd : pb_;
        pi[2] = hi ? pc_ : sa;
        pi[3] = hi ? pd_ : sb;
        const bf16x8 pf = __builtin_bit_cast(bf16x8, pi);
#pragma unroll
        for (int dt = 0; dt < 4; ++dt) {
          const int rd = (dt << 5) + (l & 31);
          const bf16x8 vf = *(const bf16x8*)((const char*)Vs + (rd << 7) +
                                             (((ks << 5) + (hi << 4)) ^ ((rd & 7) << 4)));
          o[dt] = mfma32(vf, pf, o[dt]);
        }
      }
    }
  }
  // ---- epilogue: lane q = l&31, d = dt*32 + (r&3) + 8*(r>>2) + 4*hi ----
  const float rinv = 1.0f / lrun;
  const int b = bh >> 4, h = bh & 15;
  const int qg = q0 + (w << 5) + (l & 31);
  bf16* Arow = Ao + (((size_t)(b * S + qg)) << 11) + (h << 7);
#pragma unroll
  for (int dt = 0; dt < 4; ++dt)
#pragma unroll
    for (int g = 0; g < 4; ++g) {
      bf16x4 ov;
#pragma unroll
      for (int r = 0; r < 4; ++r) ov[r] = (bf16)(o[dt][(g << 2) + r] * rinv);
      *(bf16x4*)(Arow + (dt << 5) + (g << 3) + (hi << 2)) = ov;
    }
}

// ---------------- launch ----------------
extern "C" void kernel_launch(void* const* d_in, const int* in_sizes, int n_in,
                              void* d_out, int out_size, void* d_ws, size_t ws_size,
                              hipStream_t stream) {
  const float* x = (const float*)d_in[0];      // [2,2048,2048]
  const float* w_qkv = (const float*)d_in[1];  // [6144,2048]
  const float* w_o = (const float*)d_in[2];    // [2048,2048]
  float* out = (float*)d_out;                  // [2,2048,2048] f32
  char* ws = (char*)d_ws;

  bf16* xb    = (bf16*)(ws);
  bf16* wqkvb = (bf16*)(ws + (16ull << 20));
  bf16* wob   = (bf16*)(ws + (40ull << 20));
  bf16* Qb    = (bf16*)(ws + (48ull << 20));
  bf16* Kb    = (bf16*)(ws + (64ull << 20));
  bf16* Vt    = (bf16*)(ws + (80ull << 20));
  bf16* Ao    = (bf16*)(ws + (96ull << 20));
  float* ctab = (float*)(ws + (112ull << 20));
  float* stab = (float*)(ws + (113ull << 20));

  cvt_f32_bf16<<<4096, 256, 0, stream>>>(x, xb, 2 * 2048 * 2048);
  cvt_f32_bf16<<<6144, 256, 0, stream>>>(w_qkv, wqkvb, 6144 * 2048);
  cvt_f32_bf16<<<2048, 256, 0, stream>>>(w_o, wob, 2048 * 2048);
  rope_table<<<512, 256, 0, stream>>>(ctab, stab);
  gemm256<24><<<384, 512, 0, stream>>>(xb, wqkvb, Qb, Kb, Vt);
  rope_apply<<<4096, 256, 0, stream>>>(Qb, Kb, ctab, stab);
  attn_kernel<<<512, 256, 0, stream>>>(Qb, Kb, Vt, Ao);
  gemm_bt<16><<<512, 256, 0, stream>>>(Ao, wob, out);
}

// Round 7
// 277.865 us; speedup vs baseline: 1.1327x; 1.0235x over previous
//
#include <hip/hip_runtime.h>
#include <hip/hip_bf16.h>

// SimpleAttention fused block on MI355X (gfx950), bf16 MFMA pipeline.
// B=2, S=2048, D_MODEL=2048, H=16, DK=128.
//
// R7: GEMMs -> 128x256 tile, BK=32, TRIPLE-buffered LDS (72 KiB), ONE barrier
//     per K-tile, counted vmcnt(3), 2 blocks/CU (launch_bounds 512,4).
//     Grid: QKV 768 blocks (3 clean rounds), out-proj 256 (1 round).
//     Attention: double-buffered K/V with prefetch-before-compute (T3-minimal)
//     + setprio around MFMA clusters.
//
// ws layout (bytes):          size
//  xb      [4096,2048] bf16    16M @ 0
//  wqkvb   [6144,2048] bf16    24M @ 16M
//  wob     [2048,2048] bf16     8M @ 40M
//  Qb  [B,H,S,128] bf16        16M @ 48M
//  Kb  [B,H,S,128] bf16        16M @ 64M
//  Vt  [B,H,128,S] bf16        16M @ 80M
//  Ao  [B,S,2048]  bf16        16M @ 96M
//  ctab [2048,64] f32         512K @ 112M
//  stab [2048,64] f32         512K @ 113M

typedef __bf16 bf16;
typedef __bf16 bf16x4 __attribute__((ext_vector_type(4)));
typedef __bf16 bf16x8 __attribute__((ext_vector_type(8)));
typedef float f32x4 __attribute__((ext_vector_type(4)));
typedef float f32x16 __attribute__((ext_vector_type(16)));
typedef int i32x4 __attribute__((ext_vector_type(4)));

#define DEV __device__ __forceinline__

DEV void gll16(const void* g, void* lds_base_wave_uniform) {
  __builtin_amdgcn_global_load_lds((const __attribute__((address_space(1))) void*)g,
                                   (__attribute__((address_space(3))) void*)lds_base_wave_uniform,
                                   16, 0, 0);
}

DEV f32x4 mfma16(bf16x8 a, bf16x8 b, f32x4 c) {
  return __builtin_amdgcn_mfma_f32_16x16x32_bf16(a, b, c, 0, 0, 0);
}
DEV f32x16 mfma32(bf16x8 a, bf16x8 b, f32x16 c) {
  return __builtin_amdgcn_mfma_f32_32x32x16_bf16(a, b, c, 0, 0, 0);
}

DEV int pack2(float x, float y) {
  union { bf16 h[2]; int i; } u;
  u.h[0] = (bf16)x; u.h[1] = (bf16)y;
  return u.i;
}

// ---------------- f32 -> bf16 convert ----------------
__global__ __launch_bounds__(256) void cvt_f32_bf16(const float* __restrict__ in,
                                                    bf16* __restrict__ out, int n) {
  int i = (blockIdx.x * 256 + threadIdx.x) << 3;
  if (i >= n) return;
  float4 a = *(const float4*)(in + i);
  float4 b = *(const float4*)(in + i + 4);
  bf16x8 o;
  o[0] = (bf16)a.x; o[1] = (bf16)a.y; o[2] = (bf16)a.z; o[3] = (bf16)a.w;
  o[4] = (bf16)b.x; o[5] = (bf16)b.y; o[6] = (bf16)b.z; o[7] = (bf16)b.w;
  *(bf16x8*)(out + i) = o;
}

// ---------------- rope tables ----------------
// freq[j] = 10000^(-j/63)  (linspace(0,1,64) inclusive!)
__global__ __launch_bounds__(256) void rope_table(float* __restrict__ ctab,
                                                  float* __restrict__ stab) {
  int id = blockIdx.x * 256 + threadIdx.x;  // 2048*64
  int s = id >> 6, j = id & 63;
  float freq = powf(10000.0f, -(float)j / 63.0f);
  float th = (float)s * freq;
  ctab[id] = cosf(th);
  stab[id] = sinf(th);
}

// ---------------- in-place rope on Qb (with scale) and Kb, bf16x8 ----------------
__global__ __launch_bounds__(256) void rope_apply(bf16* __restrict__ Qb, bf16* __restrict__ Kb,
                                                  const float* __restrict__ ctab,
                                                  const float* __restrict__ stab) {
  const float QSCALE = 0.08838834764831845f * 1.4426950408889634f;
  int id = blockIdx.x * 256 + threadIdx.x;  // 2 * 32*2048*8
  const int half = 32 * 2048 * 8;
  bf16* P = (id < half) ? Qb : Kb;
  const float scale = (id < half) ? QSCALE : 1.0f;
  int t = (id < half) ? id : id - half;
  const int d0 = (t & 7) << 3;        // 8 rotary pairs per thread
  const int s = (t >> 3) & 2047;
  const int bh = t >> 14;
  bf16* p = P + (((size_t)bh * 2048 + s) << 7);
  bf16x8 x1 = *(bf16x8*)(p + d0);
  bf16x8 x2 = *(bf16x8*)(p + d0 + 64);
  float4 ca = *(const float4*)(ctab + (s << 6) + d0);
  float4 cb = *(const float4*)(ctab + (s << 6) + d0 + 4);
  float4 sa = *(const float4*)(stab + (s << 6) + d0);
  float4 sb = *(const float4*)(stab + (s << 6) + d0 + 4);
  const float c[8] = {ca.x, ca.y, ca.z, ca.w, cb.x, cb.y, cb.z, cb.w};
  const float sn[8] = {sa.x, sa.y, sa.z, sa.w, sb.x, sb.y, sb.z, sb.w};
  bf16x8 y1, y2;
#pragma unroll
  for (int j = 0; j < 8; ++j) {
    const float a = (float)x1[j], b = (float)x2[j];
    y1[j] = (bf16)((a * c[j] - b * sn[j]) * scale);
    y2[j] = (bf16)((a * sn[j] + b * c[j]) * scale);
  }
  *(bf16x8*)(p + d0) = y1;
  *(bf16x8*)(p + d0 + 64) = y2;
}

// ---------------- 128x256 BK=32 triple-buffer GEMM: C = A * Bt^T ----------------
// A[M,2048], Bt[N,2048] bf16 row-major. 8 waves (wm=w>>2 in {0,1}, wn=w&3),
// per-wave C = 64x64 (acc[4][4], 64 VGPR). LDS: 3 bufs x 24 KiB (A 8K + B 16K),
// 64B rows folded into 128B superrows, slot-XOR swizzle. Per K-tile (64 total):
// {8 ds_read_b128 | stage tile t+2 (3 gll16) | lgkmcnt | 16 MFMA | vmcnt(3) |
//  ONE barrier}. Distance-2 staging legal by 3 buffers; per-wave FIFO vmcnt(3)
// proves stage(t+1) landed before the barrier.
// MODE 0: scatter to Qb/Kb ([B,H,S,128]) + Vt ([B,H,128,S]).  MODE 1: f32 C.
template <int NTN, int MODE>  // NTN = N/256; M fixed 4096 (32 tiles)
__global__ __launch_bounds__(512, 4) void gemm_p(const bf16* __restrict__ A,
                                                 const bf16* __restrict__ Bt,
                                                 bf16* __restrict__ q_out,
                                                 bf16* __restrict__ k_out,
                                                 bf16* __restrict__ v_out,
                                                 float* __restrict__ f_out) {
  constexpr int K = 2048, NKT = K / 32;  // 64 K-tiles
  constexpr int BUFB = 24576;            // bytes per buffer (A 8192 + B 16384)
  __shared__ bf16 lds[3 * 12288];
  const int nwg = NTN * 32;
  const int id = blockIdx.x;
  const int swz = (id & 7) * (nwg >> 3) + (id >> 3);  // XCD swizzle (nwg%8==0)
  const int bx = swz % NTN, by = swz / NTN;
  const int m0 = by << 7, n0 = bx << 8;
  const int tid = threadIdx.x, w = tid >> 6, l = tid & 63;
  const int wm = w >> 2, wn = w & 3;

  // staging source decode: lane l writes LDS (superrow w*8+(l>>3), phys slot l&7);
  // logical slot = phys ^ (superrow&7) -> (row parity, 8-elem col group).
  const int lsl = (l & 7) ^ ((l >> 3) & 7);
  const int srow = ((l >> 3) << 1) + (lsl >> 2);  // row within 16-row chunk
  const int scol = (lsl & 3) << 3;                // elem col 0/8/16/24

  auto STAGE = [&](int t, char* base) {
    const int k0 = t << 5;
    {  // A: 128 rows, wave w covers rows w*16..+15
      const int row = (w << 4) + srow;
      gll16(A + (size_t)(m0 + row) * K + k0 + scol, base + (w << 10));
    }
#pragma unroll
    for (int s2 = 0; s2 < 2; ++s2) {  // B: 256 rows
      const int row = (s2 << 7) + (w << 4) + srow;
      gll16(Bt + (size_t)(n0 + row) * K + k0 + scol, base + 8192 + (s2 << 13) + (w << 10));
    }
  };

  f32x4 acc[4][4] = {};

  STAGE(0, (char*)lds);
  STAGE(1, (char*)lds + BUFB);
  asm volatile("s_waitcnt vmcnt(3)" ::: "memory");
  __builtin_amdgcn_s_barrier();

#pragma unroll 1
  for (int t = 0, bi = 0, bj = 2; t < NKT; ++t) {
    char* rbase = (char*)lds + bi * BUFB;
    bf16x8 af[4], bfr[4];
#pragma unroll
    for (int i = 0; i < 4; ++i) {
      const int row = (wm << 6) + (i << 4) + (l & 15);
      const int sr = row >> 1;
      af[i] = *(const bf16x8*)(rbase + sr * 128 +
                               (((((row & 1) << 2) | (l >> 4)) ^ (sr & 7)) << 4));
    }
#pragma unroll
    for (int j = 0; j < 4; ++j) {
      const int row = (wn << 6) + (j << 4) + (l & 15);
      const int sr = row >> 1;
      bfr[j] = *(const bf16x8*)(rbase + 8192 + sr * 128 +
                                (((((row & 1) << 2) | (l >> 4)) ^ (sr & 7)) << 4));
    }
    if (t + 2 < NKT) STAGE(t + 2, (char*)lds + bj * BUFB);
    asm volatile("s_waitcnt lgkmcnt(0)" ::: "memory");
    __builtin_amdgcn_s_setprio(1);
#pragma unroll
    for (int i = 0; i < 4; ++i)
#pragma unroll
      for (int j = 0; j < 4; ++j)
        acc[i][j] = mfma16(af[i], bfr[j], acc[i][j]);
    __builtin_amdgcn_s_setprio(0);
    if (t + 2 < NKT) {
      asm volatile("s_waitcnt vmcnt(3)" ::: "memory");
    } else if (t + 2 == NKT) {
      asm volatile("s_waitcnt vmcnt(0)" ::: "memory");
    }
    __builtin_amdgcn_sched_barrier(0);
    __builtin_amdgcn_s_barrier();
    bi = (bi == 2) ? 0 : bi + 1;
    bj = (bj == 2) ? 0 : bj + 1;
  }

  // epilogue: frag (i,j): m = m0+wm*64+i*16+(l>>4)*4+r, n = n0+wn*64+j*16+(l&15)
  if constexpr (MODE == 0) {
    const int which = n0 >> 11;  // 0=Q 1=K 2=V (256-tile within one region)
    const int h = ((n0 + (wn << 6)) >> 7) & 15;
    const int dlo = ((wn & 1) << 6);
    if (which < 2) {
      bf16* dst = which ? k_out : q_out;
#pragma unroll
      for (int i = 0; i < 4; ++i)
#pragma unroll
        for (int j = 0; j < 4; ++j) {
          const int d = dlo + (j << 4) + (l & 15);
#pragma unroll
          for (int r = 0; r < 4; ++r) {
            const int m = m0 + (wm << 6) + (i << 4) + ((l >> 4) << 2) + r;
            const int b_ = m >> 11, s = m & 2047;
            dst[(((size_t)((b_ << 4) | h)) * 2048 + s) * 128 + d] = (bf16)acc[i][j][r];
          }
        }
    } else {
#pragma unroll
      for (int i = 0; i < 4; ++i)
#pragma unroll
        for (int j = 0; j < 4; ++j) {
          const int d = dlo + (j << 4) + (l & 15);
          const int sb = m0 + (wm << 6) + (i << 4) + ((l >> 4) << 2);
          const int b_ = sb >> 11, s = sb & 2047;
          bf16x4 vv;
#pragma unroll
          for (int r = 0; r < 4; ++r) vv[r] = (bf16)acc[i][j][r];
          *(bf16x4*)(v_out + ((size_t)((b_ << 4) | h) << 18) + ((size_t)d << 11) + s) = vv;
        }
    }
  } else {
#pragma unroll
    for (int i = 0; i < 4; ++i)
#pragma unroll
      for (int j = 0; j < 4; ++j)
#pragma unroll
        for (int r = 0; r < 4; ++r) {
          const int m = m0 + (wm << 6) + (i << 4) + ((l >> 4) << 2) + r;
          const int n = n0 + (wn << 6) + (j << 4) + (l & 15);
          f_out[(size_t)m * 2048 + n] = acc[i][j][r];
        }
  }
}

// ---------------- causal flash attention, swapped-operand 32x32 ----------------
// grid 512 = B*H*16 q-tiles; 4 waves x QBLK=32 rows = QB 128; KVBLK=64.
// Double-buffered K/V: next tile's 8 gll16 issued BEFORE compute; the
// __syncthreads drain is covered by QK^T+softmax+PV. setprio around MFMA.
__global__ __launch_bounds__(256, 2) void attn_kernel(const bf16* __restrict__ Qb,
                                                      const bf16* __restrict__ Kb,
                                                      const bf16* __restrict__ Vt,
                                                      bf16* __restrict__ Ao) {
  constexpr int S = 2048;
  __shared__ bf16 Ks[2][64 * 128];  // [kv][d], 256B rows, swizzled (16 KiB each)
  __shared__ bf16 Vs[2][128 * 64];  // [d][kv], 128B rows, swizzled
  const int idx = blockIdx.x;
  const int bh = idx >> 4;
  int qt = idx & 15;
  if (idx & 256) qt = 15 - qt;  // balance causal triangle
  const int q0 = qt << 7;
  const int tid = threadIdx.x, w = tid >> 6, l = tid & 63;
  const int hi = l >> 5;
  const bf16* Qp = Qb + ((size_t)bh << 18);
  const bf16* Kp = Kb + ((size_t)bh << 18);
  const bf16* Vp = Vt + ((size_t)bh << 18);

  auto STAGE_KV = [&](int kv0, int bufi) {
    char* Kbase = (char*)Ks + (bufi << 14);
    char* Vbase = (char*)Vs + (bufi << 14);
#pragma unroll
    for (int i = 0; i < 4; ++i) {
      const int rk = (w << 4) + (i << 2) + (l >> 4);  // K: 4 rows x 256B
      gll16(Kp + ((size_t)(kv0 + rk) << 7) + (((l & 15) ^ (rk & 7)) << 3),
            Kbase + (w << 12) + (i << 10));
      const int rv = (w << 5) + (i << 3) + (l >> 3);  // V: 8 rows x 128B
      gll16(Vp + (size_t)rv * S + kv0 + (((l & 7) ^ (rv & 7)) << 3),
            Vbase + (w << 12) + (i << 10));
    }
  };

  // Q fragments: lane holds q-row q0+w*32+(l&31), k = kt*16 + hi*8 .. +8
  bf16x8 qf[8];
#pragma unroll
  for (int kt = 0; kt < 8; ++kt)
    qf[kt] = *(const bf16x8*)(Qp + ((size_t)(q0 + (w << 5) + (l & 31)) << 7) + (kt << 4) + (hi << 3));

  f32x16 o[4] = {};
  float mrun = -3e38f, lrun = 0.f;

  const int qminw = q0 + (w << 5);
  const int qmaxw = qminw + 31;
  const int kv_end = q0 + 128;

  STAGE_KV(0, 0);
  __syncthreads();

  int bufi = 0;
#pragma unroll 1
  for (int kv0 = 0; kv0 < kv_end; kv0 += 64, bufi ^= 1) {
    if (kv0 + 64 < kv_end) STAGE_KV(kv0 + 64, bufi ^ 1);
    if (kv0 <= qmaxw) {
      const char* Kbase = (const char*)Ks + (bufi << 14);
      const char* Vbase = (const char*)Vs + (bufi << 14);
      // ---- S^T = K x Q^T : q = lane&31 ----
      f32x16 sc0 = {}, sc1 = {};
      __builtin_amdgcn_s_setprio(1);
#pragma unroll
      for (int kt = 0; kt < 8; ++kt) {
        const int rk0 = l & 31;
        const int coff = ((kt << 5) + (hi << 4));
        bf16x8 k0 = *(const bf16x8*)(Kbase + (rk0 << 8) + (coff ^ ((rk0 & 7) << 4)));
        bf16x8 k1 = *(const bf16x8*)(Kbase + ((rk0 + 32) << 8) + (coff ^ ((rk0 & 7) << 4)));
        sc0 = mfma32(k0, qf[kt], sc0);
        sc1 = mfma32(k1, qf[kt], sc1);
      }
      __builtin_amdgcn_s_setprio(0);
      // ---- causal mask: needed iff tile's max kv exceeds wave's MIN q ----
      if (kv0 + 63 > qminw) {
        const int qg = qminw + (l & 31);
#pragma unroll
        for (int r = 0; r < 16; ++r) {
          const int kvr = kv0 + (r & 3) + ((r >> 2) << 3) + (hi << 2);
          if (kvr > qg) sc0[r] = -3e38f;
          if (kvr + 32 > qg) sc1[r] = -3e38f;
        }
      }
      // ---- online softmax ----
      float mx = -3e38f;
#pragma unroll
      for (int r = 0; r < 16; ++r) mx = fmaxf(mx, fmaxf(sc0[r], sc1[r]));
      mx = fmaxf(mx, __shfl_xor(mx, 32));
      const float mnew = fmaxf(mrun, mx);
      if (!__all(mx <= mrun)) {
        const float alpha = exp2f(mrun - mnew);
        lrun *= alpha;
#pragma unroll
        for (int dt = 0; dt < 4; ++dt) o[dt] *= alpha;
      }
      mrun = mnew;
      float ps = 0.f;
#pragma unroll
      for (int r = 0; r < 16; ++r) {
        sc0[r] = exp2f(sc0[r] - mnew); ps += sc0[r];
        sc1[r] = exp2f(sc1[r] - mnew); ps += sc1[r];
      }
      ps += __shfl_xor(ps, 32);
      lrun += ps;
      // ---- O^T += V^T x P^T ----
#pragma unroll
      for (int ks = 0; ks < 4; ++ks) {
        const f32x16& s = (ks & 2) ? sc1 : sc0;
        const int rb = (ks & 1) << 3;
        int pa_ = pack2(s[rb + 0], s[rb + 1]);
        int pb_ = pack2(s[rb + 2], s[rb + 3]);
        int pc_ = pack2(s[rb + 4], s[rb + 5]);
        int pd_ = pack2(s[rb + 6], s[rb + 7]);
        int sa = __shfl_xor(pa_, 32), sb = __shfl_xor(pb_, 32);
        int sc_ = __shfl_xor(pc_, 32), sd = __shfl_xor(pd_, 32);
        i32x4 pi;
        pi[0] = hi ? sc_ : pa_;
        pi[1] = hi ? sd : pb_;
        pi[2] = hi ? pc_ : sa;
        pi[3] = hi ? pd_ : sb;
        const bf16x8 pf = __builtin_bit_cast(bf16x8, pi);
        __builtin_amdgcn_s_setprio(1);
#pragma unroll
        for (int dt = 0; dt < 4; ++dt) {
          const int rd = (dt << 5) + (l & 31);
          const bf16x8 vf = *(const bf16x8*)(Vbase + (rd << 7) +
                                             (((ks << 5) + (hi << 4)) ^ ((rd & 7) << 4)));
          o[dt] = mfma32(vf, pf, o[dt]);
        }
        __builtin_amdgcn_s_setprio(0);
      }
    }
    __syncthreads();
  }
  // ---- epilogue: lane q = l&31, d = dt*32 + (r&3) + 8*(r>>2) + 4*hi ----
  const float rinv = 1.0f / lrun;
  const int b = bh >> 4, h = bh & 15;
  const int qg = q0 + (w << 5) + (l & 31);
  bf16* Arow = Ao + (((size_t)(b * S + qg)) << 11) + (h << 7);
#pragma unroll
  for (int dt = 0; dt < 4; ++dt)
#pragma unroll
    for (int g = 0; g < 4; ++g) {
      bf16x4 ov;
#pragma unroll
      for (int r = 0; r < 4; ++r) ov[r] = (bf16)(o[dt][(g << 2) + r] * rinv);
      *(bf16x4*)(Arow + (dt << 5) + (g << 3) + (hi << 2)) = ov;
    }
}

// ---------------- launch ----------------
extern "C" void kernel_launch(void* const* d_in, const int* in_sizes, int n_in,
                              void* d_out, int out_size, void* d_ws, size_t ws_size,
                              hipStream_t stream) {
  const float* x = (const float*)d_in[0];      // [2,2048,2048]
  const float* w_qkv = (const float*)d_in[1];  // [6144,2048]
  const float* w_o = (const float*)d_in[2];    // [2048,2048]
  float* out = (float*)d_out;                  // [2,2048,2048] f32
  char* ws = (char*)d_ws;

  bf16* xb    = (bf16*)(ws);
  bf16* wqkvb = (bf16*)(ws + (16ull << 20));
  bf16* wob   = (bf16*)(ws + (40ull << 20));
  bf16* Qb    = (bf16*)(ws + (48ull << 20));
  bf16* Kb    = (bf16*)(ws + (64ull << 20));
  bf16* Vt    = (bf16*)(ws + (80ull << 20));
  bf16* Ao    = (bf16*)(ws + (96ull << 20));
  float* ctab = (float*)(ws + (112ull << 20));
  float* stab = (float*)(ws + (113ull << 20));

  cvt_f32_bf16<<<4096, 256, 0, stream>>>(x, xb, 2 * 2048 * 2048);
  cvt_f32_bf16<<<6144, 256, 0, stream>>>(w_qkv, wqkvb, 6144 * 2048);
  cvt_f32_bf16<<<2048, 256, 0, stream>>>(w_o, wob, 2048 * 2048);
  rope_table<<<512, 256, 0, stream>>>(ctab, stab);
  gemm_p<24, 0><<<768, 512, 0, stream>>>(xb, wqkvb, Qb, Kb, Vt, nullptr);
  rope_apply<<<4096, 256, 0, stream>>>(Qb, Kb, ctab, stab);
  attn_kernel<<<512, 256, 0, stream>>>(Qb, Kb, Vt, Ao);
  gemm_p<8, 1><<<256, 512, 0, stream>>>(Ao, wob, nullptr, nullptr, nullptr, out);
}

// Round 8
// 255.578 us; speedup vs baseline: 1.2315x; 1.0872x over previous
//
#include <hip/hip_runtime.h>
#include <hip/hip_bf16.h>

// SimpleAttention fused block on MI355X (gfx950), bf16 MFMA pipeline.
// B=2, S=2048, D_MODEL=2048, H=16, DK=128.
//
// R8: QKV -> 256x384 tile, BK=32, triple-buffer 120 KiB, grid 256 = exactly
//     one round (no tail imbalance), 48 MFMA per K-tile per wave in two
//     24-MFMA clusters (reg cap). Out-proj stays 128x256 gemm_p. Attention
//     unchanged (dbuf prefetch + setprio).
//
// ws layout (bytes):          size
//  xb      [4096,2048] bf16    16M @ 0
//  wqkvb   [6144,2048] bf16    24M @ 16M
//  wob     [2048,2048] bf16     8M @ 40M
//  Qb  [B,H,S,128] bf16        16M @ 48M
//  Kb  [B,H,S,128] bf16        16M @ 64M
//  Vt  [B,H,128,S] bf16        16M @ 80M
//  Ao  [B,S,2048]  bf16        16M @ 96M
//  ctab [2048,64] f32         512K @ 112M
//  stab [2048,64] f32         512K @ 113M

typedef __bf16 bf16;
typedef __bf16 bf16x4 __attribute__((ext_vector_type(4)));
typedef __bf16 bf16x8 __attribute__((ext_vector_type(8)));
typedef float f32x4 __attribute__((ext_vector_type(4)));
typedef float f32x16 __attribute__((ext_vector_type(16)));
typedef int i32x4 __attribute__((ext_vector_type(4)));

#define DEV __device__ __forceinline__

DEV void gll16(const void* g, void* lds_base_wave_uniform) {
  __builtin_amdgcn_global_load_lds((const __attribute__((address_space(1))) void*)g,
                                   (__attribute__((address_space(3))) void*)lds_base_wave_uniform,
                                   16, 0, 0);
}

DEV f32x4 mfma16(bf16x8 a, bf16x8 b, f32x4 c) {
  return __builtin_amdgcn_mfma_f32_16x16x32_bf16(a, b, c, 0, 0, 0);
}
DEV f32x16 mfma32(bf16x8 a, bf16x8 b, f32x16 c) {
  return __builtin_amdgcn_mfma_f32_32x32x16_bf16(a, b, c, 0, 0, 0);
}

DEV int pack2(float x, float y) {
  union { bf16 h[2]; int i; } u;
  u.h[0] = (bf16)x; u.h[1] = (bf16)y;
  return u.i;
}

// ---------------- f32 -> bf16 convert ----------------
__global__ __launch_bounds__(256) void cvt_f32_bf16(const float* __restrict__ in,
                                                    bf16* __restrict__ out, int n) {
  int i = (blockIdx.x * 256 + threadIdx.x) << 3;
  if (i >= n) return;
  float4 a = *(const float4*)(in + i);
  float4 b = *(const float4*)(in + i + 4);
  bf16x8 o;
  o[0] = (bf16)a.x; o[1] = (bf16)a.y; o[2] = (bf16)a.z; o[3] = (bf16)a.w;
  o[4] = (bf16)b.x; o[5] = (bf16)b.y; o[6] = (bf16)b.z; o[7] = (bf16)b.w;
  *(bf16x8*)(out + i) = o;
}

// ---------------- rope tables ----------------
// freq[j] = 10000^(-j/63)  (linspace(0,1,64) inclusive!)
__global__ __launch_bounds__(256) void rope_table(float* __restrict__ ctab,
                                                  float* __restrict__ stab) {
  int id = blockIdx.x * 256 + threadIdx.x;  // 2048*64
  int s = id >> 6, j = id & 63;
  float freq = powf(10000.0f, -(float)j / 63.0f);
  float th = (float)s * freq;
  ctab[id] = cosf(th);
  stab[id] = sinf(th);
}

// ---------------- in-place rope on Qb (with scale) and Kb, bf16x8 ----------------
__global__ __launch_bounds__(256) void rope_apply(bf16* __restrict__ Qb, bf16* __restrict__ Kb,
                                                  const float* __restrict__ ctab,
                                                  const float* __restrict__ stab) {
  const float QSCALE = 0.08838834764831845f * 1.4426950408889634f;
  int id = blockIdx.x * 256 + threadIdx.x;  // 2 * 32*2048*8
  const int half = 32 * 2048 * 8;
  bf16* P = (id < half) ? Qb : Kb;
  const float scale = (id < half) ? QSCALE : 1.0f;
  int t = (id < half) ? id : id - half;
  const int d0 = (t & 7) << 3;        // 8 rotary pairs per thread
  const int s = (t >> 3) & 2047;
  const int bh = t >> 14;
  bf16* p = P + (((size_t)bh * 2048 + s) << 7);
  bf16x8 x1 = *(bf16x8*)(p + d0);
  bf16x8 x2 = *(bf16x8*)(p + d0 + 64);
  float4 ca = *(const float4*)(ctab + (s << 6) + d0);
  float4 cb = *(const float4*)(ctab + (s << 6) + d0 + 4);
  float4 sa = *(const float4*)(stab + (s << 6) + d0);
  float4 sb = *(const float4*)(stab + (s << 6) + d0 + 4);
  const float c[8] = {ca.x, ca.y, ca.z, ca.w, cb.x, cb.y, cb.z, cb.w};
  const float sn[8] = {sa.x, sa.y, sa.z, sa.w, sb.x, sb.y, sb.z, sb.w};
  bf16x8 y1, y2;
#pragma unroll
  for (int j = 0; j < 8; ++j) {
    const float a = (float)x1[j], b = (float)x2[j];
    y1[j] = (bf16)((a * c[j] - b * sn[j]) * scale);
    y2[j] = (bf16)((a * sn[j] + b * c[j]) * scale);
  }
  *(bf16x8*)(p + d0) = y1;
  *(bf16x8*)(p + d0 + 64) = y2;
}

// ---------------- 256x384 BK=32 triple-buffer GEMM (QKV): C = A * Bt^T -------
// Grid 16x16 = 256 blocks (one clean round, 1 block/CU, 8 waves = 2/SIMD).
// Waves 2M x 4N: per-wave C = 128x96 = acc[8][6] (AGPR). Per K-tile:
// {6 B-frag + 4 A-frag ds_read | STAGE t+2 (5 gll16) | 24 MFMA | 4 A-frag |
//  24 MFMA | vmcnt(5) | barrier}. Distance-2 staging, triple buffer, counted
// vmcnt FIFO. LDS rows: 2x32-elem rows folded per 128B superrow, slot-XOR.
__global__ __launch_bounds__(512, 2) void gemm384(const bf16* __restrict__ A,
                                                  const bf16* __restrict__ Bt,
                                                  bf16* __restrict__ q_out,
                                                  bf16* __restrict__ k_out,
                                                  bf16* __restrict__ v_out) {
  constexpr int K = 2048, NKT = 64;
  constexpr int BUFB = 40960;  // A 16384 + B 24576
  __shared__ char lds[3 * BUFB];  // 120 KiB
  const int id = blockIdx.x;
  const int swz = (id & 7) * 32 + (id >> 3);  // XCD swizzle (256 blocks)
  const int bx = swz & 15, by = swz >> 4;
  const int m0 = by << 8;      // 256-row M tile
  const int n0 = bx * 384;     // 384-col N tile
  const int tid = threadIdx.x, w = tid >> 6, l = tid & 63;
  const int wm = w >> 2, wn = w & 3;
  // staging decode (same as R7; verified 0 bank conflicts)
  const int lsl = (l & 7) ^ ((l >> 3) & 7);
  const int srow = ((l >> 3) << 1) + (lsl >> 2);
  const int scol = (lsl & 3) << 3;

  auto STAGE = [&](int t, char* base) {
    const int k0 = t << 5;
#pragma unroll
    for (int c = 0; c < 2; ++c) {  // A: 256 rows = 2 issues
      const int row = (c << 7) + (w << 4) + srow;
      gll16(A + (size_t)(m0 + row) * K + k0 + scol, base + (c << 13) + (w << 10));
    }
#pragma unroll
    for (int c = 0; c < 3; ++c) {  // B: 384 rows = 3 issues
      const int row = (c << 7) + (w << 4) + srow;
      gll16(Bt + (size_t)(n0 + row) * K + k0 + scol, base + 16384 + (c << 13) + (w << 10));
    }
  };

  f32x4 acc[8][6] = {};

  STAGE(0, (char*)lds);
  STAGE(1, (char*)lds + BUFB);
  asm volatile("s_waitcnt vmcnt(5)" ::: "memory");
  __builtin_amdgcn_s_barrier();

#pragma unroll 1
  for (int t = 0, bi = 0, bj = 2; t < NKT; ++t) {
    char* rbase = (char*)lds + bi * BUFB;
    bf16x8 bfr[6];
#pragma unroll
    for (int j = 0; j < 6; ++j) {
      const int row = wn * 96 + (j << 4) + (l & 15);
      const int sr = row >> 1;
      bfr[j] = *(const bf16x8*)(rbase + 16384 + sr * 128 +
                                (((((row & 1) << 2) | (l >> 4)) ^ (sr & 7)) << 4));
    }
    bf16x8 af[4];
#pragma unroll
    for (int i = 0; i < 4; ++i) {
      const int row = (wm << 7) + (i << 4) + (l & 15);
      const int sr = row >> 1;
      af[i] = *(const bf16x8*)(rbase + sr * 128 +
                               (((((row & 1) << 2) | (l >> 4)) ^ (sr & 7)) << 4));
    }
    if (t + 2 < NKT) STAGE(t + 2, (char*)lds + bj * BUFB);
    asm volatile("s_waitcnt lgkmcnt(0)" ::: "memory");
    __builtin_amdgcn_sched_barrier(0);
    __builtin_amdgcn_s_setprio(1);
#pragma unroll
    for (int i = 0; i < 4; ++i)
#pragma unroll
      for (int j = 0; j < 6; ++j)
        acc[i][j] = mfma16(af[i], bfr[j], acc[i][j]);
    __builtin_amdgcn_s_setprio(0);
#pragma unroll
    for (int i = 0; i < 4; ++i) {  // A frag-rows 4..7
      const int row = (wm << 7) + 64 + (i << 4) + (l & 15);
      const int sr = row >> 1;
      af[i] = *(const bf16x8*)(rbase + sr * 128 +
                               (((((row & 1) << 2) | (l >> 4)) ^ (sr & 7)) << 4));
    }
    asm volatile("s_waitcnt lgkmcnt(0)" ::: "memory");
    __builtin_amdgcn_sched_barrier(0);
    __builtin_amdgcn_s_setprio(1);
#pragma unroll
    for (int i = 0; i < 4; ++i)
#pragma unroll
      for (int j = 0; j < 6; ++j)
        acc[4 + i][j] = mfma16(af[i], bfr[j], acc[4 + i][j]);
    __builtin_amdgcn_s_setprio(0);
    if (t + 2 < NKT) {
      asm volatile("s_waitcnt vmcnt(5)" ::: "memory");
    } else if (t + 2 == NKT) {
      asm volatile("s_waitcnt vmcnt(0)" ::: "memory");
    }
    __builtin_amdgcn_sched_barrier(0);
    __builtin_amdgcn_s_barrier();
    bi = (bi == 2) ? 0 : bi + 1;
    bj = (bj == 2) ? 0 : bj + 1;
  }

  // epilogue: frag (i,j): m = m0+wm*128+i*16+(l>>4)*4+r, nl = n0+wn*96+j*16+(l&15)
  // 384-tile straddles Q/K/V 2048-boundaries -> decide region per j-frag.
#pragma unroll
  for (int i = 0; i < 8; ++i)
#pragma unroll
    for (int j = 0; j < 6; ++j) {
      const int nl = n0 + wn * 96 + (j << 4) + (l & 15);
      const int which = nl >> 11;
      const int h = (nl >> 7) & 15, d = nl & 127;
      if (which < 2) {
        bf16* dst = which ? k_out : q_out;
#pragma unroll
        for (int r = 0; r < 4; ++r) {
          const int m = m0 + (wm << 7) + (i << 4) + ((l >> 4) << 2) + r;
          const int b_ = m >> 11, s = m & 2047;
          dst[(((size_t)((b_ << 4) | h)) * 2048 + s) * 128 + d] = (bf16)acc[i][j][r];
        }
      } else {
        const int sb = m0 + (wm << 7) + (i << 4) + ((l >> 4) << 2);
        const int b_ = sb >> 11, s = sb & 2047;
        bf16x4 vv;
#pragma unroll
        for (int r = 0; r < 4; ++r) vv[r] = (bf16)acc[i][j][r];
        *(bf16x4*)(v_out + ((size_t)((b_ << 4) | h) << 18) + ((size_t)d << 11) + s) = vv;
      }
    }
}

// ---------------- 128x256 BK=32 triple-buffer GEMM (out-proj), f32 out -------
template <int NTN, int MODE>  // NTN = N/256
__global__ __launch_bounds__(512, 4) void gemm_p(const bf16* __restrict__ A,
                                                 const bf16* __restrict__ Bt,
                                                 bf16* __restrict__ q_out,
                                                 bf16* __restrict__ k_out,
                                                 bf16* __restrict__ v_out,
                                                 float* __restrict__ f_out) {
  constexpr int K = 2048, NKT = K / 32;
  constexpr int BUFB = 24576;
  __shared__ bf16 lds[3 * 12288];
  const int nwg = NTN * 32;
  const int id = blockIdx.x;
  const int swz = (id & 7) * (nwg >> 3) + (id >> 3);
  const int bx = swz % NTN, by = swz / NTN;
  const int m0 = by << 7, n0 = bx << 8;
  const int tid = threadIdx.x, w = tid >> 6, l = tid & 63;
  const int wm = w >> 2, wn = w & 3;
  const int lsl = (l & 7) ^ ((l >> 3) & 7);
  const int srow = ((l >> 3) << 1) + (lsl >> 2);
  const int scol = (lsl & 3) << 3;

  auto STAGE = [&](int t, char* base) {
    const int k0 = t << 5;
    {
      const int row = (w << 4) + srow;
      gll16(A + (size_t)(m0 + row) * K + k0 + scol, base + (w << 10));
    }
#pragma unroll
    for (int s2 = 0; s2 < 2; ++s2) {
      const int row = (s2 << 7) + (w << 4) + srow;
      gll16(Bt + (size_t)(n0 + row) * K + k0 + scol, base + 8192 + (s2 << 13) + (w << 10));
    }
  };

  f32x4 acc[4][4] = {};

  STAGE(0, (char*)lds);
  STAGE(1, (char*)lds + BUFB);
  asm volatile("s_waitcnt vmcnt(3)" ::: "memory");
  __builtin_amdgcn_s_barrier();

#pragma unroll 1
  for (int t = 0, bi = 0, bj = 2; t < NKT; ++t) {
    char* rbase = (char*)lds + bi * BUFB;
    bf16x8 af[4], bfr[4];
#pragma unroll
    for (int i = 0; i < 4; ++i) {
      const int row = (wm << 6) + (i << 4) + (l & 15);
      const int sr = row >> 1;
      af[i] = *(const bf16x8*)(rbase + sr * 128 +
                               (((((row & 1) << 2) | (l >> 4)) ^ (sr & 7)) << 4));
    }
#pragma unroll
    for (int j = 0; j < 4; ++j) {
      const int row = (wn << 6) + (j << 4) + (l & 15);
      const int sr = row >> 1;
      bfr[j] = *(const bf16x8*)(rbase + 8192 + sr * 128 +
                                (((((row & 1) << 2) | (l >> 4)) ^ (sr & 7)) << 4));
    }
    if (t + 2 < NKT) STAGE(t + 2, (char*)lds + bj * BUFB);
    asm volatile("s_waitcnt lgkmcnt(0)" ::: "memory");
    __builtin_amdgcn_s_setprio(1);
#pragma unroll
    for (int i = 0; i < 4; ++i)
#pragma unroll
      for (int j = 0; j < 4; ++j)
        acc[i][j] = mfma16(af[i], bfr[j], acc[i][j]);
    __builtin_amdgcn_s_setprio(0);
    if (t + 2 < NKT) {
      asm volatile("s_waitcnt vmcnt(3)" ::: "memory");
    } else if (t + 2 == NKT) {
      asm volatile("s_waitcnt vmcnt(0)" ::: "memory");
    }
    __builtin_amdgcn_sched_barrier(0);
    __builtin_amdgcn_s_barrier();
    bi = (bi == 2) ? 0 : bi + 1;
    bj = (bj == 2) ? 0 : bj + 1;
  }

  if constexpr (MODE == 0) {
    const int which = n0 >> 11;
    const int h = ((n0 + (wn << 6)) >> 7) & 15;
    const int dlo = ((wn & 1) << 6);
    if (which < 2) {
      bf16* dst = which ? k_out : q_out;
#pragma unroll
      for (int i = 0; i < 4; ++i)
#pragma unroll
        for (int j = 0; j < 4; ++j) {
          const int d = dlo + (j << 4) + (l & 15);
#pragma unroll
          for (int r = 0; r < 4; ++r) {
            const int m = m0 + (wm << 6) + (i << 4) + ((l >> 4) << 2) + r;
            const int b_ = m >> 11, s = m & 2047;
            dst[(((size_t)((b_ << 4) | h)) * 2048 + s) * 128 + d] = (bf16)acc[i][j][r];
          }
        }
    } else {
#pragma unroll
      for (int i = 0; i < 4; ++i)
#pragma unroll
        for (int j = 0; j < 4; ++j) {
          const int d = dlo + (j << 4) + (l & 15);
          const int sb = m0 + (wm << 6) + (i << 4) + ((l >> 4) << 2);
          const int b_ = sb >> 11, s = sb & 2047;
          bf16x4 vv;
#pragma unroll
          for (int r = 0; r < 4; ++r) vv[r] = (bf16)acc[i][j][r];
          *(bf16x4*)(v_out + ((size_t)((b_ << 4) | h) << 18) + ((size_t)d << 11) + s) = vv;
        }
    }
  } else {
#pragma unroll
    for (int i = 0; i < 4; ++i)
#pragma unroll
      for (int j = 0; j < 4; ++j)
#pragma unroll
        for (int r = 0; r < 4; ++r) {
          const int m = m0 + (wm << 6) + (i << 4) + ((l >> 4) << 2) + r;
          const int n = n0 + (wn << 6) + (j << 4) + (l & 15);
          f_out[(size_t)m * 2048 + n] = acc[i][j][r];
        }
  }
}

// ---------------- causal flash attention, swapped-operand 32x32 ----------------
// grid 512 = B*H*16 q-tiles; 4 waves x QBLK=32 rows = QB 128; KVBLK=64.
// Double-buffered K/V: next tile's 8 gll16 issued BEFORE compute; setprio.
__global__ __launch_bounds__(256, 2) void attn_kernel(const bf16* __restrict__ Qb,
                                                      const bf16* __restrict__ Kb,
                                                      const bf16* __restrict__ Vt,
                                                      bf16* __restrict__ Ao) {
  constexpr int S = 2048;
  __shared__ bf16 Ks[2][64 * 128];
  __shared__ bf16 Vs[2][128 * 64];
  const int idx = blockIdx.x;
  const int bh = idx >> 4;
  int qt = idx & 15;
  if (idx & 256) qt = 15 - qt;
  const int q0 = qt << 7;
  const int tid = threadIdx.x, w = tid >> 6, l = tid & 63;
  const int hi = l >> 5;
  const bf16* Qp = Qb + ((size_t)bh << 18);
  const bf16* Kp = Kb + ((size_t)bh << 18);
  const bf16* Vp = Vt + ((size_t)bh << 18);

  auto STAGE_KV = [&](int kv0, int bufi) {
    char* Kbase = (char*)Ks + (bufi << 14);
    char* Vbase = (char*)Vs + (bufi << 14);
#pragma unroll
    for (int i = 0; i < 4; ++i) {
      const int rk = (w << 4) + (i << 2) + (l >> 4);
      gll16(Kp + ((size_t)(kv0 + rk) << 7) + (((l & 15) ^ (rk & 7)) << 3),
            Kbase + (w << 12) + (i << 10));
      const int rv = (w << 5) + (i << 3) + (l >> 3);
      gll16(Vp + (size_t)rv * S + kv0 + (((l & 7) ^ (rv & 7)) << 3),
            Vbase + (w << 12) + (i << 10));
    }
  };

  bf16x8 qf[8];
#pragma unroll
  for (int kt = 0; kt < 8; ++kt)
    qf[kt] = *(const bf16x8*)(Qp + ((size_t)(q0 + (w << 5) + (l & 31)) << 7) + (kt << 4) + (hi << 3));

  f32x16 o[4] = {};
  float mrun = -3e38f, lrun = 0.f;

  const int qminw = q0 + (w << 5);
  const int qmaxw = qminw + 31;
  const int kv_end = q0 + 128;

  STAGE_KV(0, 0);
  __syncthreads();

  int bufi = 0;
#pragma unroll 1
  for (int kv0 = 0; kv0 < kv_end; kv0 += 64, bufi ^= 1) {
    if (kv0 + 64 < kv_end) STAGE_KV(kv0 + 64, bufi ^ 1);
    if (kv0 <= qmaxw) {
      const char* Kbase = (const char*)Ks + (bufi << 14);
      const char* Vbase = (const char*)Vs + (bufi << 14);
      f32x16 sc0 = {}, sc1 = {};
      __builtin_amdgcn_s_setprio(1);
#pragma unroll
      for (int kt = 0; kt < 8; ++kt) {
        const int rk0 = l & 31;
        const int coff = ((kt << 5) + (hi << 4));
        bf16x8 k0 = *(const bf16x8*)(Kbase + (rk0 << 8) + (coff ^ ((rk0 & 7) << 4)));
        bf16x8 k1 = *(const bf16x8*)(Kbase + ((rk0 + 32) << 8) + (coff ^ ((rk0 & 7) << 4)));
        sc0 = mfma32(k0, qf[kt], sc0);
        sc1 = mfma32(k1, qf[kt], sc1);
      }
      __builtin_amdgcn_s_setprio(0);
      if (kv0 + 63 > qminw) {
        const int qg = qminw + (l & 31);
#pragma unroll
        for (int r = 0; r < 16; ++r) {
          const int kvr = kv0 + (r & 3) + ((r >> 2) << 3) + (hi << 2);
          if (kvr > qg) sc0[r] = -3e38f;
          if (kvr + 32 > qg) sc1[r] = -3e38f;
        }
      }
      float mx = -3e38f;
#pragma unroll
      for (int r = 0; r < 16; ++r) mx = fmaxf(mx, fmaxf(sc0[r], sc1[r]));
      mx = fmaxf(mx, __shfl_xor(mx, 32));
      const float mnew = fmaxf(mrun, mx);
      if (!__all(mx <= mrun)) {
        const float alpha = exp2f(mrun - mnew);
        lrun *= alpha;
#pragma unroll
        for (int dt = 0; dt < 4; ++dt) o[dt] *= alpha;
      }
      mrun = mnew;
      float ps = 0.f;
#pragma unroll
      for (int r = 0; r < 16; ++r) {
        sc0[r] = exp2f(sc0[r] - mnew); ps += sc0[r];
        sc1[r] = exp2f(sc1[r] - mnew); ps += sc1[r];
      }
      ps += __shfl_xor(ps, 32);
      lrun += ps;
#pragma unroll
      for (int ks = 0; ks < 4; ++ks) {
        const f32x16& s = (ks & 2) ? sc1 : sc0;
        const int rb = (ks & 1) << 3;
        int pa_ = pack2(s[rb + 0], s[rb + 1]);
        int pb_ = pack2(s[rb + 2], s[rb + 3]);
        int pc_ = pack2(s[rb + 4], s[rb + 5]);
        int pd_ = pack2(s[rb + 6], s[rb + 7]);
        int sa = __shfl_xor(pa_, 32), sb = __shfl_xor(pb_, 32);
        int sc_ = __shfl_xor(pc_, 32), sd = __shfl_xor(pd_, 32);
        i32x4 pi;
        pi[0] = hi ? sc_ : pa_;
        pi[1] = hi ? sd : pb_;
        pi[2] = hi ? pc_ : sa;
        pi[3] = hi ? pd_ : sb;
        const bf16x8 pf = __builtin_bit_cast(bf16x8, pi);
        __builtin_amdgcn_s_setprio(1);
#pragma unroll
        for (int dt = 0; dt < 4; ++dt) {
          const int rd = (dt << 5) + (l & 31);
          const bf16x8 vf = *(const bf16x8*)(Vbase + (rd << 7) +
                                             (((ks << 5) + (hi << 4)) ^ ((rd & 7) << 4)));
          o[dt] = mfma32(vf, pf, o[dt]);
        }
        __builtin_amdgcn_s_setprio(0);
      }
    }
    __syncthreads();
  }
  const float rinv = 1.0f / lrun;
  const int b = bh >> 4, h = bh & 15;
  const int qg = q0 + (w << 5) + (l & 31);
  bf16* Arow = Ao + (((size_t)(b * S + qg)) << 11) + (h << 7);
#pragma unroll
  for (int dt = 0; dt < 4; ++dt)
#pragma unroll
    for (int g = 0; g < 4; ++g) {
      bf16x4 ov;
#pragma unroll
      for (int r = 0; r < 4; ++r) ov[r] = (bf16)(o[dt][(g << 2) + r] * rinv);
      *(bf16x4*)(Arow + (dt << 5) + (g << 3) + (hi << 2)) = ov;
    }
}

// ---------------- launch ----------------
extern "C" void kernel_launch(void* const* d_in, const int* in_sizes, int n_in,
                              void* d_out, int out_size, void* d_ws, size_t ws_size,
                              hipStream_t stream) {
  const float* x = (const float*)d_in[0];      // [2,2048,2048]
  const float* w_qkv = (const float*)d_in[1];  // [6144,2048]
  const float* w_o = (const float*)d_in[2];    // [2048,2048]
  float* out = (float*)d_out;                  // [2,2048,2048] f32
  char* ws = (char*)d_ws;

  bf16* xb    = (bf16*)(ws);
  bf16* wqkvb = (bf16*)(ws + (16ull << 20));
  bf16* wob   = (bf16*)(ws + (40ull << 20));
  bf16* Qb    = (bf16*)(ws + (48ull << 20));
  bf16* Kb    = (bf16*)(ws + (64ull << 20));
  bf16* Vt    = (bf16*)(ws + (80ull << 20));
  bf16* Ao    = (bf16*)(ws + (96ull << 20));
  float* ctab = (float*)(ws + (112ull << 20));
  float* stab = (float*)(ws + (113ull << 20));

  cvt_f32_bf16<<<4096, 256, 0, stream>>>(x, xb, 2 * 2048 * 2048);
  cvt_f32_bf16<<<6144, 256, 0, stream>>>(w_qkv, wqkvb, 6144 * 2048);
  cvt_f32_bf16<<<2048, 256, 0, stream>>>(w_o, wob, 2048 * 2048);
  rope_table<<<512, 256, 0, stream>>>(ctab, stab);
  gemm384<<<256, 512, 0, stream>>>(xb, wqkvb, Qb, Kb, Vt);
  rope_apply<<<4096, 256, 0, stream>>>(Qb, Kb, ctab, stab);
  attn_kernel<<<512, 256, 0, stream>>>(Qb, Kb, Vt, Ao);
  gemm_p<8, 1><<<256, 512, 0, stream>>>(Ao, wob, nullptr, nullptr, nullptr, out);
}